// Round 11
// baseline (592.912 us; speedup 1.0000x reference)
//
#include <hip/hip_runtime.h>
#include <hip/hip_bf16.h>

// Problem constants (B=1)
#define CL 2048   // sequence length
#define CD 1024   // hidden
#define CH 16     // heads
#define CHD 64    // head dim
#define NEGS -1e30f

typedef __attribute__((ext_vector_type(8))) short short8;  // 8 x bf16 frag
typedef __attribute__((ext_vector_type(4))) float f32x4;
// One row of scores per WAVE (32 regs), static indices everywhere.
typedef __attribute__((ext_vector_type(32))) float f32x32;

__device__ __forceinline__ float wave_sum(float x) {
#pragma unroll
  for (int m = 32; m >= 1; m >>= 1) x += __shfl_xor(x, m, 64);
  return x;
}
__device__ __forceinline__ float wave_max(float x) {
#pragma unroll
  for (int m = 32; m >= 1; m >>= 1) x = fmaxf(x, __shfl_xor(x, m, 64));
  return x;
}

__device__ __forceinline__ void split1(float v, short& h, short& l) {
  __hip_bfloat16 bh = __float2bfloat16(v);
  __hip_bfloat16 bl = __float2bfloat16(v - __bfloat162float(bh));
  h = __builtin_bit_cast(short, bh);
  l = __builtin_bit_cast(short, bl);
}
__device__ __forceinline__ unsigned short bf16_bits(float v) {
  __hip_bfloat16 b = __float2bfloat16(v);
  return (unsigned short)__builtin_bit_cast(short, b);
}

// ---- depth-5 tree helpers over f32x32 ----
__device__ __forceinline__ float tree_sum_valid(const f32x32& s) {
  float t[8];
#pragma unroll
  for (int i = 0; i < 8; i++) {
    const float a = s[i]      > -1e29f ? s[i]      : 0.f;
    const float b = s[i + 8]  > -1e29f ? s[i + 8]  : 0.f;
    const float c = s[i + 16] > -1e29f ? s[i + 16] : 0.f;
    const float d = s[i + 24] > -1e29f ? s[i + 24] : 0.f;
    t[i] = (a + b) + (c + d);
  }
#pragma unroll
  for (int i = 0; i < 4; i++) t[i] += t[i + 4];
  t[0] += t[2]; t[1] += t[3];
  return t[0] + t[1];
}
__device__ __forceinline__ float tree_max(const f32x32& s) {
  float t[8];
#pragma unroll
  for (int i = 0; i < 8; i++)
    t[i] = fmaxf(fmaxf(s[i], s[i + 8]), fmaxf(s[i + 16], s[i + 24]));
#pragma unroll
  for (int i = 0; i < 4; i++) t[i] = fmaxf(t[i], t[i + 4]);
  return fmaxf(fmaxf(t[0], t[2]), fmaxf(t[1], t[3]));
}
__device__ __forceinline__ void masked_sc(const f32x32& s, float tau,
                                          float& cs, float& cn) {
  float ts[8], tc[8];
#pragma unroll
  for (int i = 0; i < 8; i++) {
    const float a = s[i], b = s[i + 8], c = s[i + 16], d = s[i + 24];
    ts[i] = ((a > tau ? a : 0.f) + (b > tau ? b : 0.f)) +
            ((c > tau ? c : 0.f) + (d > tau ? d : 0.f));
    tc[i] = ((a > tau ? 1.f : 0.f) + (b > tau ? 1.f : 0.f)) +
            ((c > tau ? 1.f : 0.f) + (d > tau ? 1.f : 0.f));
  }
#pragma unroll
  for (int i = 0; i < 4; i++) { ts[i] += ts[i + 4]; tc[i] += tc[i + 4]; }
  ts[0] += ts[2]; ts[1] += ts[3]; tc[0] += tc[2]; tc[1] += tc[3];
  cs = ts[0] + ts[1];
  cn = tc[0] + tc[1];
}
__device__ __forceinline__ float relu_store_sum(f32x32& s, float ts_) {
  float t[8];
#pragma unroll
  for (int i = 0; i < 8; i++) {
    float a = s[i] - ts_;      a = a > 0.f ? a : 0.f;
    float b = s[i + 8] - ts_;  b = b > 0.f ? b : 0.f;
    float c = s[i + 16] - ts_; c = c > 0.f ? c : 0.f;
    float d = s[i + 24] - ts_; d = d > 0.f ? d : 0.f;
    s[i] = a; s[i + 8] = b; s[i + 16] = c; s[i + 24] = d;
    t[i] = (a + b) + (c + d);
  }
#pragma unroll
  for (int i = 0; i < 4; i++) t[i] += t[i + 4];
  t[0] += t[2]; t[1] += t[3];
  return t[0] + t[1];
}

// Single-row warm-start Michelot (R9-verified numerics). tau* in
// [max-1, max-1/n] => {s > max-1.000001} is a superset of the support;
// fixpoint count == reference's sort-based k_support. Reference quirk:
// tau_star = (FULL masked sum - 1)/cnt. Overwrites s with unnormalized p.
__device__ __forceinline__ float entmax1(f32x32& s) {
  const float ss = wave_sum(tree_sum_valid(s));
  const float m = wave_max(tree_max(s));
  float tau = m - 1.000001f;
  int cnt = 0;
  for (int it = 0; it < 64; it++) {
    float cs, cn;
    masked_sc(s, tau, cs, cn);
    cs = wave_sum(cs);
    cn = wave_sum(cn);
    const int nc = (int)cn;
    if (nc == cnt) break;   // wave-uniform
    cnt = nc;
    tau = (cs - 1.f) / cn;
  }
  const float ts = (ss - 1.f) / (float)cnt;
  return 1.f / (wave_sum(relu_store_sum(s, ts)) + 1e-10f);
}

// One fused split kernel: fp32 -> bf16 hi/lo planes for x and 4 weights.
__global__ __launch_bounds__(256) void split_all(
    const float* __restrict__ x,  const float* __restrict__ wq,
    const float* __restrict__ wk, const float* __restrict__ wv,
    const float* __restrict__ wo,
    short* __restrict__ xh,  short* __restrict__ xl,
    short* __restrict__ wqh, short* __restrict__ wql,
    short* __restrict__ wkh, short* __restrict__ wkl,
    short* __restrict__ wvh, short* __restrict__ wvl,
    short* __restrict__ woh, short* __restrict__ wol) {
  const int b = blockIdx.x;
  const float* src; short *dh, *dl; int i0;
  if      (b < 2048) { src = x;  dh = xh;  dl = xl;  i0 = b; }
  else if (b < 3072) { src = wq; dh = wqh; dl = wql; i0 = b - 2048; }
  else if (b < 4096) { src = wk; dh = wkh; dl = wkl; i0 = b - 3072; }
  else if (b < 5120) { src = wv; dh = wvh; dl = wvl; i0 = b - 4096; }
  else               { src = wo; dh = woh; dl = wol; i0 = b - 5120; }
  const int i = i0 * 256 + threadIdx.x;
  const float4 v = reinterpret_cast<const float4*>(src)[i];
  const float vv[4] = {v.x, v.y, v.z, v.w};
  short hh[4], ll[4];
#pragma unroll
  for (int e = 0; e < 4; e++) split1(vv[e], hh[e], ll[e]);
  reinterpret_cast<short4*>(dh)[i] = make_short4(hh[0], hh[1], hh[2], hh[3]);
  reinterpret_cast<short4*>(dl)[i] = make_short4(ll[0], ll[1], ll[2], ll[3]);
}

// C[2048,1024] = (Ah+Al) * (B?h+B?l)^T via 3-term split-bf16 MFMA.
// 128x128 tile/WG, LDS-staged BK=32. Epilogue: fp32out -> Cf; else bf16 hi/lo
// planes (sel 2 = vT transposed [dim][seq] for the P@V B-operand).
__global__ __launch_bounds__(256, 2) void gemm128_split(
    const short* __restrict__ Ah, const short* __restrict__ Al,
    const short* __restrict__ B0h, const short* __restrict__ B0l,
    const short* __restrict__ B1h, const short* __restrict__ B1l,
    const short* __restrict__ B2h, const short* __restrict__ B2l,
    short* __restrict__ O0h, short* __restrict__ O0l,
    short* __restrict__ O1h, short* __restrict__ O1l,
    short* __restrict__ O2h, short* __restrict__ O2l,
    float* __restrict__ Cf, int fp32out) {
  __shared__ short AhS[128][32], AlS[128][32], BhS[128][32], BlS[128][32];
  const int tid = threadIdx.x, lane = tid & 63, wave = tid >> 6;
  const int l15 = lane & 15, quad = lane >> 4;
  const int sel = blockIdx.x >> 3, nb = blockIdx.x & 7;
  const short* Bh = sel == 0 ? B0h : (sel == 1 ? B1h : B2h);
  const short* Bl = sel == 0 ? B0l : (sel == 1 ? B1l : B2l);
  const int m0 = blockIdx.y * 128, n0 = nb * 128;
  const int wm = (wave >> 1) * 64, wn = (wave & 1) * 64;

  f32x4 acc[4][4];
#pragma unroll
  for (int i = 0; i < 4; i++)
#pragma unroll
    for (int j = 0; j < 4; j++) acc[i][j] = {0.f, 0.f, 0.f, 0.f};

  const short* gsrc = wave == 0 ? Ah : wave == 1 ? Al : wave == 2 ? Bh : Bl;
  short(*ldst)[32] = wave == 0 ? AhS : wave == 1 ? AlS : wave == 2 ? BhS : BlS;
  const int srow0 = (wave < 2) ? m0 : n0;

  for (int k0 = 0; k0 < CD; k0 += 32) {
#pragma unroll
    for (int i = 0; i < 8; i++) {
      const int ci = i * 64 + lane;
      const int r = ci >> 2, kc = (ci & 3) * 8;
      *reinterpret_cast<short8*>(&ldst[r][kc]) =
          *reinterpret_cast<const short8*>(&gsrc[(size_t)(srow0 + r) * CD + k0 + kc]);
    }
    __syncthreads();
    short8 a_h[4], a_l[4], b_h[4], b_l[4];
#pragma unroll
    for (int i = 0; i < 4; i++) {
      a_h[i] = *reinterpret_cast<const short8*>(&AhS[wm + i * 16 + l15][quad * 8]);
      a_l[i] = *reinterpret_cast<const short8*>(&AlS[wm + i * 16 + l15][quad * 8]);
      b_h[i] = *reinterpret_cast<const short8*>(&BhS[wn + i * 16 + l15][quad * 8]);
      b_l[i] = *reinterpret_cast<const short8*>(&BlS[wn + i * 16 + l15][quad * 8]);
    }
#pragma unroll
    for (int im = 0; im < 4; im++)
#pragma unroll
      for (int in = 0; in < 4; in++) {
        acc[im][in] = __builtin_amdgcn_mfma_f32_16x16x32_bf16(a_h[im], b_l[in], acc[im][in], 0, 0, 0);
        acc[im][in] = __builtin_amdgcn_mfma_f32_16x16x32_bf16(a_l[im], b_h[in], acc[im][in], 0, 0, 0);
        acc[im][in] = __builtin_amdgcn_mfma_f32_16x16x32_bf16(a_h[im], b_h[in], acc[im][in], 0, 0, 0);
      }
    __syncthreads();
  }

#pragma unroll
  for (int im = 0; im < 4; im++)
#pragma unroll
    for (int in = 0; in < 4; in++)
#pragma unroll
      for (int r = 0; r < 4; r++) {
        const int mr = m0 + wm + im * 16 + quad * 4 + r;
        const int nc = n0 + wn + in * 16 + l15;
        const float val = acc[im][in][r];
        if (fp32out) {
          Cf[(size_t)mr * CD + nc] = val;
        } else {
          short sh, sl;
          split1(val, sh, sl);
          if (sel == 0) {
            O0h[(size_t)mr * CD + nc] = sh; O0l[(size_t)mr * CD + nc] = sl;
          } else if (sel == 1) {
            O1h[(size_t)mr * CD + nc] = sh; O1l[(size_t)mr * CD + nc] = sl;
          } else {  // vT[dim][seq]
            O2h[(size_t)nc * CL + mr] = sh; O2l[(size_t)nc * CL + mr] = sl;
          }
        }
      }
}

// WG = 512 thr (8 waves) x (head h, 8 query rows). Wave w owns row q0+w.
// Small LDS (15 KB) + small barriers -> high co-residency (R9's winning lever
// was occupancy: 16%->36% gave 475->336; push toward the 32-wave cap).
// Phase 1: 128-col tiles; wave w computes col-block w via *4-term* split MFMA.
//   R10 LESSON: the SCORE path must keep all 4 terms (al*bl included) — the
//   3-term variant flipped a support row (absmax 0.047). Smooth paths (P@V,
//   projections) may use 3-term; scores may not.
// Phase 2: 8 rows' Michelot fully parallel, one wave each.
// Phase 3: P single-plane bf16 in LDS; wave = (kgroup w>>2, dim-block w&3);
//   vT hi/lo B-frags from global; one LDS partial-reduce at the end.
__global__ __launch_bounds__(512, 4) void attn8(
    const short* __restrict__ qh, const short* __restrict__ ql,
    const short* __restrict__ kh, const short* __restrict__ kl,
    const short* __restrict__ vhT, const short* __restrict__ vlT,
    short* __restrict__ oh, short* __restrict__ ol) {
  __shared__ float Stile[8][260];            // 8.3 KB; scatter/gather <=2-way
  __shared__ unsigned short Ptile[8][136];   // 2.1 KB; rows 272B (16B-aligned)
  __shared__ float Rtile[2][8][68];          // 4.4 KB partial PV
  __shared__ float invS[8];

  const int tid = threadIdx.x, lane = tid & 63, wave = tid >> 6;
  const int l15 = lane & 15, quad = lane >> 4;
  const int bx = blockIdx.x;
  const int qb = (bx & 1) ? (255 - (bx >> 1)) : (bx >> 1);  // heavy+light mix
  const int h = blockIdx.y, q0 = qb * 8, col0 = h * CHD;
  const int grow = q0 + wave;                 // this wave's global q-row
  const int ntiles = (q0 + 135) >> 7;         // 128-col tiles covering 0..q0+7

  // Q A-frags: rows q0 + (l15&7) (rows 8-15 duplicate), k=kb*32+quad*8+j
  short8 a_h[2], a_l[2];
  {
    const size_t qbase = (size_t)(q0 + (l15 & 7)) * CD + col0 + quad * 8;
#pragma unroll
    for (int kb = 0; kb < 2; kb++) {
      a_h[kb] = *reinterpret_cast<const short8*>(qh + qbase + kb * 32);
      a_l[kb] = *reinterpret_cast<const short8*>(ql + qbase + kb * 32);
    }
  }

  f32x32 s;
#pragma unroll
  for (int t = 0; t < 32; t++) s[t] = NEGS;

  // ---- Phase 1: scores (4-term: exact (qh+ql)(kh+kl), R9 numerics) ----
#pragma unroll
  for (int jt = 0; jt < 16; jt++) {
    if (jt < ntiles) {                        // WG-uniform
      const int j0 = jt * 128;
      // B-frags: K rows j0 + 16*wave + l15 (this wave's 16 seq-cols)
      const size_t kbase = (size_t)(j0 + 16 * wave + l15) * CD + col0 + quad * 8;
      f32x4 c = {0.f, 0.f, 0.f, 0.f};
#pragma unroll
      for (int kb = 0; kb < 2; kb++) {
        const short8 b_h = *reinterpret_cast<const short8*>(kh + kbase + kb * 32);
        const short8 b_l = *reinterpret_cast<const short8*>(kl + kbase + kb * 32);
        c = __builtin_amdgcn_mfma_f32_16x16x32_bf16(a_l[kb], b_l, c, 0, 0, 0);
        c = __builtin_amdgcn_mfma_f32_16x16x32_bf16(a_h[kb], b_l, c, 0, 0, 0);
        c = __builtin_amdgcn_mfma_f32_16x16x32_bf16(a_l[kb], b_h, c, 0, 0, 0);
        c = __builtin_amdgcn_mfma_f32_16x16x32_bf16(a_h[kb], b_h, c, 0, 0, 0);
      }
      // C layout: col(seq) = 16*wave + l15, row(q) = quad*4 + r (rows 0..7 valid)
      if (quad < 2) {
#pragma unroll
        for (int r = 0; r < 4; r++) Stile[quad * 4 + r][16 * wave + l15] = c[r];
      }
      __syncthreads();
      // Gather MY row: lane ll owns cols j0 + 64*tt + ll (2-way, free)
#pragma unroll
      for (int tt = 0; tt < 2; tt++) {
        const int col = j0 + 64 * tt + lane;
        const float v = Stile[wave][64 * tt + lane] * 0.125f;  // 2^-3: exact
        s[jt * 2 + tt] = (col <= grow) ? v : NEGS;
      }
      __syncthreads();
    }
  }

  // ---- Phase 2: entmax, 8 rows fully parallel (one wave each) ----
  const float inv = entmax1(s);
  if (lane == 0) invS[wave] = inv;

  // ---- Phase 3: P @ V (wave = (kgroup, dim-block)) ----
  f32x4 acc = {0.f, 0.f, 0.f, 0.f};
  const int db = wave & 3, kcg = wave >> 2;
#pragma unroll
  for (int jt = 0; jt < 16; jt++) {
    if (jt < ntiles) {
      // write MY row's p for this tile (bf16; zeros where masked)
#pragma unroll
      for (int tt = 0; tt < 2; tt++)
        Ptile[wave][64 * tt + lane] = bf16_bits(s[jt * 2 + tt]);
      __syncthreads();
      const size_t vrowbase = (size_t)(col0 + 16 * db + l15) * CL + jt * 128;
#pragma unroll
      for (int t2 = 0; t2 < 2; t2++) {
        const int kc = 2 * kcg + t2;  // this wave's K-chunk of 32
        const short8 pa = *reinterpret_cast<const short8*>(
            &Ptile[l15 & 7][kc * 32 + quad * 8]);  // rows 8-15 duplicate
        const size_t vb = vrowbase + kc * 32 + quad * 8;
        const short8 vbh = *reinterpret_cast<const short8*>(vhT + vb);
        const short8 vbl = *reinterpret_cast<const short8*>(vlT + vb);
        acc = __builtin_amdgcn_mfma_f32_16x16x32_bf16(pa, vbl, acc, 0, 0, 0);
        acc = __builtin_amdgcn_mfma_f32_16x16x32_bf16(pa, vbh, acc, 0, 0, 0);
      }
      __syncthreads();
    }
  }

  // ---- Cross-wave K-group reduce + epilogue ----
  if (quad < 2) {  // valid C rows 0..7
#pragma unroll
    for (int r = 0; r < 4; r++) Rtile[kcg][quad * 4 + r][db * 16 + l15] = acc[r];
  }
  __syncthreads();
  if (wave < 4) {  // wave u handles dim-block u; quad q handles rows 2q,2q+1
#pragma unroll
    for (int rr = 0; rr < 2; rr++) {
      const int row = quad * 2 + rr;
      float o = Rtile[0][row][wave * 16 + l15] + Rtile[1][row][wave * 16 + l15];
      o *= invS[row];
      short sh, sl;
      split1(o, sh, sl);
      const size_t oidx = (size_t)(q0 + row) * CD + col0 + wave * 16 + l15;
      oh[oidx] = sh;
      ol[oidx] = sl;
    }
  }
}

extern "C" void kernel_launch(void* const* d_in, const int* in_sizes, int n_in,
                              void* d_out, int out_size, void* d_ws, size_t ws_size,
                              hipStream_t stream) {
  const float* x  = (const float*)d_in[0];
  const float* Wq = (const float*)d_in[1];
  const float* Wk = (const float*)d_in[2];
  const float* Wv = (const float*)d_in[3];
  const float* Wo = (const float*)d_in[4];
  float* out = (float*)d_out;

  // Workspace layout (56 MB total)
  char* ws = (char*)d_ws;
  short* xh  = (short*)(ws + (0ull  << 20));
  short* xl  = (short*)(ws + (4ull  << 20));
  short* wqh = (short*)(ws + (8ull  << 20));
  short* wql = (short*)(ws + (10ull << 20));
  short* wkh = (short*)(ws + (12ull << 20));
  short* wkl = (short*)(ws + (14ull << 20));
  short* wvh = (short*)(ws + (16ull << 20));
  short* wvl = (short*)(ws + (18ull << 20));
  short* woh = (short*)(ws + (20ull << 20));
  short* wol = (short*)(ws + (22ull << 20));
  short* qhp = (short*)(ws + (24ull << 20));
  short* qlp = (short*)(ws + (28ull << 20));
  short* khp = (short*)(ws + (32ull << 20));
  short* klp = (short*)(ws + (36ull << 20));
  short* vhT = (short*)(ws + (40ull << 20));
  short* vlT = (short*)(ws + (44ull << 20));
  short* ohp = (short*)(ws + (48ull << 20));
  short* olp = (short*)(ws + (52ull << 20));

  split_all<<<6144, 256, 0, stream>>>(x, Wq, Wk, Wv, Wo,
                                      xh, xl, wqh, wql, wkh, wkl,
                                      wvh, wvl, woh, wol);

  // Fused QKV: grid.x = 24, sel = x>>3 -> q/k planes row-major, vT transposed
  gemm128_split<<<dim3(24, CL / 128), 256, 0, stream>>>(
      xh, xl, wqh, wql, wkh, wkl, wvh, wvl,
      qhp, qlp, khp, klp, vhT, vlT, nullptr, 0);

  attn8<<<dim3(CL / 8, CH), 512, 0, stream>>>(
      qhp, qlp, khp, klp, vhT, vlT, ohp, olp);

  // Wo: grid.x = 8 (sel = 0), fp32 out
  gemm128_split<<<dim3(8, CL / 128), 256, 0, stream>>>(
      ohp, olp, woh, wol, woh, wol, woh, wol,
      ohp, olp, ohp, olp, ohp, olp, out, 1);
}